// Round 8
// baseline (506.606 us; speedup 1.0000x reference)
//
#include <hip/hip_runtime.h>
#include <hip/hip_bf16.h>
#include <math.h>

#define T_TOK 2048
#define HD 1024
#define ID 2048
#define NE 8

typedef __attribute__((ext_vector_type(8))) short s16x8;
typedef __attribute__((ext_vector_type(8))) unsigned short u16x8;
typedef __attribute__((ext_vector_type(4))) float f32x4;
typedef __attribute__((ext_vector_type(4))) unsigned short u16x4;

__device__ __forceinline__ unsigned short f2bf(float f) {
  union { float f; unsigned u; } v; v.f = f;
  unsigned r = v.u + 0x7FFFu + ((v.u >> 16) & 1u);   // RNE
  return (unsigned short)(r >> 16);
}

__device__ __forceinline__ u16x8 pack8(float4 a, float4 b) {
  u16x8 v;
  v[0] = f2bf(a.x); v[1] = f2bf(a.y); v[2] = f2bf(a.z); v[3] = f2bf(a.w);
  v[4] = f2bf(b.x); v[5] = f2bf(b.y); v[6] = f2bf(b.z); v[7] = f2bf(b.w);
  return v;
}

#define GLOAD16(gsrc, ldst) \
  __builtin_amdgcn_global_load_lds((const __attribute__((address_space(1))) void*)(gsrc), \
                                   (__attribute__((address_space(3))) void*)(ldst), 16, 0, 0)

// ---------------- router: one wave per token ----------------
__global__ void router_k(const float* __restrict__ x, const float* __restrict__ gate,
                         int* __restrict__ cnt, int* __restrict__ tok,
                         float* __restrict__ wt, int* __restrict__ inv) {
  int wid = threadIdx.x >> 6, lane = threadIdx.x & 63;
  int t = blockIdx.x * 4 + wid;
  const float* xr = x + (size_t)t * HD;
  float acc[NE];
#pragma unroll
  for (int e = 0; e < NE; e++) acc[e] = 0.f;
  for (int h = lane; h < HD; h += 64) {
    float xv = xr[h];
#pragma unroll
    for (int e = 0; e < NE; e++) acc[e] += xv * gate[e * HD + h];
  }
#pragma unroll
  for (int e = 0; e < NE; e++)
    for (int off = 32; off; off >>= 1) acc[e] += __shfl_xor(acc[e], off);
  int i0 = 0;
#pragma unroll
  for (int e = 1; e < NE; e++) if (acc[e] > acc[i0]) i0 = e;
  int i1 = (i0 == 0) ? 1 : 0;
#pragma unroll
  for (int e = 0; e < NE; e++) if (e != i0 && acc[e] > acc[i1]) i1 = e;
  float w0 = 1.f / (1.f + expf(acc[i1] - acc[i0]));
  float w1 = 1.f - w0;
  if (lane == 0) {
    int p0 = atomicAdd(&cnt[i0], 1);
    tok[i0 * T_TOK + p0] = t; wt[i0 * T_TOK + p0] = w0;
    inv[2 * t] = (i0 << 16) | p0;
    int p1 = atomicAdd(&cnt[i1], 1);
    tok[i1 * T_TOK + p1] = t; wt[i1 * T_TOK + p1] = w1;
    inv[2 * t + 1] = (i1 << 16) | p1;
  }
}

__global__ void prefix_k(const int* __restrict__ cnt, int* __restrict__ offs) {
  if (threadIdx.x == 0) {
    int s = 0;
    for (int e = 0; e < NE; e++) { offs[e] = s; s += cnt[e]; }
  }
}

// gather token rows (fp32 -> bf16), compacted by expert
__global__ void gather_k(const float* __restrict__ x, const int* __restrict__ cnt,
                         const int* __restrict__ offs, const int* __restrict__ tok,
                         unsigned short* __restrict__ Xg) {
  int e = blockIdx.x >> 11, slot = blockIdx.x & 2047;
  if (slot >= cnt[e]) return;
  int t = tok[e * T_TOK + slot];
  int row = offs[e] + slot;
  int c = threadIdx.x * 4;
  float4 f = *(const float4*)(x + (size_t)t * HD + c);
  u16x4 o; o.x = f2bf(f.x); o.y = f2bf(f.y); o.z = f2bf(f.z); o.w = f2bf(f.w);
  *(u16x4*)(Xg + (size_t)row * HD + c) = o;
}

// ======================= grouped GEMM engine notes =======================
// BM=128 BN=64 BK=64, 256 thr (4 waves 2x2, wave tile 64x32).
// A: bf16 via global_load_lds, chunk-major LDS [chunk16][gran8][row16][16B]
//    (r6 layout, measured BANK_CONFLICT=0). Double-buffered.
// B: fp32 global -> regs -> bf16 ds_write into same chunk-major layout; the
//    ds_write's reg-dep vmcnt drain sits AFTER compute (1-phase flight).
// Phase: [stage(t+1): A gloads + B reg loads] -> compute(t) -> [cvt+write B] -> barrier.
// Grid: e = bid&7 (expert->XCD pinning); r2 = mt + 8*nt so co-resident
// mt-blocks share the same B slice (weights HBM-fetched once, rest L2).

// chunk-major elem offset helpers
// A read frag (wave row base wr*64): elem = (wr*4+m)*1024 + (kk*4+hi)*128 + l15*8
// B read frag: elem = (wc*2+n)*1024 + (kk*4+hi)*128 + l15*8

// ---------------- grouped GEMM1: act = w * silu(Xg@w1^T) * (Xg@w3^T) ----------------
__global__ __launch_bounds__(256, 2) void gemm1_k(
    const unsigned short* __restrict__ Xg, const float* __restrict__ w1,
    const float* __restrict__ w3, const int* __restrict__ cnt,
    const int* __restrict__ offs, const float* __restrict__ wt,
    unsigned short* __restrict__ act) {
  int bid = blockIdx.x;
  int e = bid & 7;
  int r2 = bid >> 3;
  int mt = r2 & 7, nt = r2 >> 3;         // mt 0..7, nt 0..31
  int count = cnt[e];
  if (mt * 128 >= count) return;
  int i0 = nt * 64;
  int rbase = offs[e] + mt * 128;
  const float* W1 = w1 + (size_t)e * ID * HD;
  const float* W3 = w3 + (size_t)e * ID * HD;

  __shared__ __align__(16) unsigned short Ab[2][8192];   // 16 KB x2
  __shared__ __align__(16) unsigned short B1b[2][4096];  // 8 KB x2
  __shared__ __align__(16) unsigned short B2b[2][4096];  // 8 KB x2  -> 64 KB total

  int tid = threadIdx.x;
  int wid = tid >> 6, lane = tid & 63;
  int wr = wid >> 1, wc = wid & 1;
  int l15 = lane & 15, hi = lane >> 4;

  // ---- A staging: 4 gload16/thread, chunk-major dest
  const unsigned short* aP[4];
  int aD[4];
#pragma unroll
  for (int j = 0; j < 4; j++) {
    int idx = wid * 4 + j;               // 0..15 wave-load slots
    int chunk = idx >> 1, half = idx & 1;
    aP[j] = Xg + (size_t)(rbase + chunk * 16 + l15) * HD + (half * 4 + hi) * 8;
    aD[j] = idx * 512 + lane * 8;        // elems
  }
  // ---- B staging: thread covers (row=tid>>2, 16 cols at gp*16)
  int rB = tid >> 2, gp = tid & 3;
  const float* s1 = W1 + (size_t)(i0 + rB) * HD + gp * 16;
  const float* s2 = W3 + (size_t)(i0 + rB) * HD + gp * 16;
  int bD = (rB >> 4) * 1024 + (2 * gp) * 128 + (rB & 15) * 8;  // elems; 2nd granule +128

  f32x4 accg[4][2], accu[4][2];
#pragma unroll
  for (int m = 0; m < 4; m++)
#pragma unroll
    for (int n = 0; n < 2; n++) {
      accg[m][n] = (f32x4){0.f, 0.f, 0.f, 0.f};
      accu[m][n] = (f32x4){0.f, 0.f, 0.f, 0.f};
    }

  // ---- prologue: tile 0
  {
#pragma unroll
    for (int j = 0; j < 4; j++) GLOAD16(aP[j], &Ab[0][aD[j]]);
    float4 f10 = *(const float4*)(s1 + 0), f11 = *(const float4*)(s1 + 4);
    float4 f12 = *(const float4*)(s1 + 8), f13 = *(const float4*)(s1 + 12);
    float4 f20 = *(const float4*)(s2 + 0), f21 = *(const float4*)(s2 + 4);
    float4 f22 = *(const float4*)(s2 + 8), f23 = *(const float4*)(s2 + 12);
    *(u16x8*)&B1b[0][bD] = pack8(f10, f11);
    *(u16x8*)&B1b[0][bD + 128] = pack8(f12, f13);
    *(u16x8*)&B2b[0][bD] = pack8(f20, f21);
    *(u16x8*)&B2b[0][bD + 128] = pack8(f22, f23);
    __syncthreads();
  }

  for (int t = 0; t < 16; ++t) {         // HD/64 = 16 K-tiles
    int cur = t & 1;
    float4 f10, f11, f12, f13, f20, f21, f22, f23;
    if (t < 15) {
      int k0 = (t + 1) * 64;
#pragma unroll
      for (int j = 0; j < 4; j++) GLOAD16(aP[j] + k0, &Ab[cur ^ 1][aD[j]]);
      f10 = *(const float4*)(s1 + k0);     f11 = *(const float4*)(s1 + k0 + 4);
      f12 = *(const float4*)(s1 + k0 + 8); f13 = *(const float4*)(s1 + k0 + 12);
      f20 = *(const float4*)(s2 + k0);     f21 = *(const float4*)(s2 + k0 + 4);
      f22 = *(const float4*)(s2 + k0 + 8); f23 = *(const float4*)(s2 + k0 + 12);
    }
    // ---- compute tile t (pure bf16 ds_read + MFMA)
#pragma unroll
    for (int kk = 0; kk < 2; ++kk) {
      s16x8 a[4], b1[2], b2[2];
#pragma unroll
      for (int m = 0; m < 4; m++)
        a[m] = *(const s16x8*)&Ab[cur][(wr * 4 + m) * 1024 + (kk * 4 + hi) * 128 + l15 * 8];
#pragma unroll
      for (int n = 0; n < 2; n++) {
        b1[n] = *(const s16x8*)&B1b[cur][(wc * 2 + n) * 1024 + (kk * 4 + hi) * 128 + l15 * 8];
        b2[n] = *(const s16x8*)&B2b[cur][(wc * 2 + n) * 1024 + (kk * 4 + hi) * 128 + l15 * 8];
      }
#pragma unroll
      for (int m = 0; m < 4; m++)
#pragma unroll
        for (int n = 0; n < 2; n++) {
          accg[m][n] = __builtin_amdgcn_mfma_f32_16x16x32_bf16(a[m], b1[n], accg[m][n], 0, 0, 0);
          accu[m][n] = __builtin_amdgcn_mfma_f32_16x16x32_bf16(a[m], b2[n], accu[m][n], 0, 0, 0);
        }
    }
    __builtin_amdgcn_sched_barrier(0);   // keep B cvt+write AFTER the MFMA cluster
    if (t < 15) {
      *(u16x8*)&B1b[cur ^ 1][bD] = pack8(f10, f11);
      *(u16x8*)&B1b[cur ^ 1][bD + 128] = pack8(f12, f13);
      *(u16x8*)&B2b[cur ^ 1][bD] = pack8(f20, f21);
      *(u16x8*)&B2b[cur ^ 1][bD + 128] = pack8(f22, f23);
    }
    __syncthreads();                      // drains A gloads (vmcnt0) + B writes visible
  }

  // epilogue: w * silu(g) * u -> bf16 act (C/D map: col=lane&15, row=(lane>>4)*4+reg)
#pragma unroll
  for (int m = 0; m < 4; m++)
#pragma unroll
    for (int r = 0; r < 4; r++) {
      int rl = mt * 128 + wr * 64 + m * 16 + hi * 4 + r;
      if (rl < count) {
        float w = wt[e * T_TOK + rl];
#pragma unroll
        for (int n = 0; n < 2; n++) {
          float g = accg[m][n][r], u = accu[m][n][r];
          float s = (g / (1.f + expf(-g))) * u * w;
          act[(size_t)(offs[e] + rl) * ID + i0 + wc * 32 + n * 16 + l15] = f2bf(s);
        }
      }
    }
}

// ---------------- grouped GEMM2: ye = act @ w2^T ----------------
__global__ __launch_bounds__(256, 3) void gemm2_k(
    const unsigned short* __restrict__ act, const float* __restrict__ w2,
    const int* __restrict__ cnt, const int* __restrict__ offs,
    float* __restrict__ ye) {
  int bid = blockIdx.x;
  int e = bid & 7;
  int r2 = bid >> 3;
  int mt = r2 & 7, nt = r2 >> 3;         // mt 0..7, nt 0..15
  int count = cnt[e];
  if (mt * 128 >= count) return;
  int h0 = nt * 64;
  int rbase = offs[e] + mt * 128;
  const float* W2 = w2 + (size_t)e * HD * ID;   // [1024][2048]

  __shared__ __align__(16) unsigned short Ab[2][8192];   // 16 KB x2
  __shared__ __align__(16) unsigned short Bb[2][4096];   // 8 KB x2  -> 48 KB

  int tid = threadIdx.x;
  int wid = tid >> 6, lane = tid & 63;
  int wr = wid >> 1, wc = wid & 1;
  int l15 = lane & 15, hi = lane >> 4;

  const unsigned short* aP[4];
  int aD[4];
#pragma unroll
  for (int j = 0; j < 4; j++) {
    int idx = wid * 4 + j;
    int chunk = idx >> 1, half = idx & 1;
    aP[j] = act + (size_t)(rbase + chunk * 16 + l15) * ID + (half * 4 + hi) * 8;
    aD[j] = idx * 512 + lane * 8;
  }
  int rB = tid >> 2, gp = tid & 3;
  const float* sB = W2 + (size_t)(h0 + rB) * ID + gp * 16;
  int bD = (rB >> 4) * 1024 + (2 * gp) * 128 + (rB & 15) * 8;

  f32x4 acc[4][2];
#pragma unroll
  for (int m = 0; m < 4; m++)
#pragma unroll
    for (int n = 0; n < 2; n++) acc[m][n] = (f32x4){0.f, 0.f, 0.f, 0.f};

  {
#pragma unroll
    for (int j = 0; j < 4; j++) GLOAD16(aP[j], &Ab[0][aD[j]]);
    float4 f0 = *(const float4*)(sB + 0), f1 = *(const float4*)(sB + 4);
    float4 f2 = *(const float4*)(sB + 8), f3 = *(const float4*)(sB + 12);
    *(u16x8*)&Bb[0][bD] = pack8(f0, f1);
    *(u16x8*)&Bb[0][bD + 128] = pack8(f2, f3);
    __syncthreads();
  }

  for (int t = 0; t < 32; ++t) {         // ID/64 = 32 K-tiles
    int cur = t & 1;
    float4 f0, f1, f2, f3;
    if (t < 31) {
      int k0 = (t + 1) * 64;
#pragma unroll
      for (int j = 0; j < 4; j++) GLOAD16(aP[j] + k0, &Ab[cur ^ 1][aD[j]]);
      f0 = *(const float4*)(sB + k0);     f1 = *(const float4*)(sB + k0 + 4);
      f2 = *(const float4*)(sB + k0 + 8); f3 = *(const float4*)(sB + k0 + 12);
    }
#pragma unroll
    for (int kk = 0; kk < 2; ++kk) {
      s16x8 a[4], b[2];
#pragma unroll
      for (int m = 0; m < 4; m++)
        a[m] = *(const s16x8*)&Ab[cur][(wr * 4 + m) * 1024 + (kk * 4 + hi) * 128 + l15 * 8];
#pragma unroll
      for (int n = 0; n < 2; n++)
        b[n] = *(const s16x8*)&Bb[cur][(wc * 2 + n) * 1024 + (kk * 4 + hi) * 128 + l15 * 8];
#pragma unroll
      for (int m = 0; m < 4; m++)
#pragma unroll
        for (int n = 0; n < 2; n++)
          acc[m][n] = __builtin_amdgcn_mfma_f32_16x16x32_bf16(a[m], b[n], acc[m][n], 0, 0, 0);
    }
    __builtin_amdgcn_sched_barrier(0);
    if (t < 31) {
      *(u16x8*)&Bb[cur ^ 1][bD] = pack8(f0, f1);
      *(u16x8*)&Bb[cur ^ 1][bD + 128] = pack8(f2, f3);
    }
    __syncthreads();
  }

#pragma unroll
  for (int m = 0; m < 4; m++)
#pragma unroll
    for (int r = 0; r < 4; r++) {
      int slot = mt * 128 + wr * 64 + m * 16 + hi * 4 + r;
      if (slot < count) {
#pragma unroll
        for (int n = 0; n < 2; n++)
          ye[(size_t)(offs[e] + slot) * HD + h0 + wc * 32 + n * 16 + l15] = acc[m][n][r];
      }
    }
}

// ---------------- combine: out[t] = ye[slot0] + ye[slot1] ----------------
__global__ void combine_k(const float* __restrict__ ye, const int* __restrict__ inv,
                          const int* __restrict__ offs, float* __restrict__ out) {
  int t = blockIdx.x;
  int c = threadIdx.x * 4;
  int v0 = inv[2 * t], v1 = inv[2 * t + 1];
  size_t r0 = (size_t)(offs[v0 >> 16] + (v0 & 0xFFFF)) * HD + c;
  size_t r1 = (size_t)(offs[v1 >> 16] + (v1 & 0xFFFF)) * HD + c;
  float4 a = *(const float4*)(ye + r0);
  float4 b = *(const float4*)(ye + r1);
  float4 o = {a.x + b.x, a.y + b.y, a.z + b.z, a.w + b.w};
  *(float4*)(out + (size_t)t * HD + c) = o;
}

extern "C" void kernel_launch(void* const* d_in, const int* in_sizes, int n_in,
                              void* d_out, int out_size, void* d_ws, size_t ws_size,
                              hipStream_t stream) {
  const float* x    = (const float*)d_in[0];
  const float* gate = (const float*)d_in[1];
  const float* w1   = (const float*)d_in[2];
  const float* w3   = (const float*)d_in[3];
  const float* w2   = (const float*)d_in[4];
  float* out = (float*)d_out;

  char* ws = (char*)d_ws;
  int* cnt  = (int*)(ws + 0);
  int* offs = (int*)(ws + 256);
  int* tok  = (int*)(ws + 512);                           // 64K
  float* wt = (float*)(ws + 66048);                       // 64K
  int* inv  = (int*)(ws + 131584);                        // 16K
  unsigned short* Xg  = (unsigned short*)(ws + 148480);   // 5120 x 1024 bf16 (pad rows for tail over-reads)
  unsigned short* act = (unsigned short*)(ws + 10634240); // 5120 x 2048 bf16
  float* ye = (float*)(ws + 31605760);                    // 4224 x 1024 f32 -> ends ~48.9M

  hipMemsetAsync(cnt, 0, 256, stream);

  router_k<<<T_TOK / 4, 256, 0, stream>>>(x, gate, cnt, tok, wt, inv);
  prefix_k<<<1, 64, 0, stream>>>(cnt, offs);
  gather_k<<<NE * T_TOK, 256, 0, stream>>>(x, cnt, offs, tok, Xg);
  // 1-D grids: e = bid&7 (expert->XCD pin); r2 = mt + 8*nt (mt-blocks co-resident share B slice)
  gemm1_k<<<NE * 8 * 32, 256, 0, stream>>>(Xg, w1, w3, cnt, offs, wt, act);
  gemm2_k<<<NE * 8 * 16, 256, 0, stream>>>(act, w2, cnt, offs, ye);
  combine_k<<<T_TOK, 256, 0, stream>>>(ye, inv, offs, out);
}